// Round 1
// baseline (1616.470 us; speedup 1.0000x reference)
//
#include <hip/hip_runtime.h>
#include <stdint.h>

typedef unsigned short u16;
typedef __attribute__((ext_vector_type(8))) __bf16 bf16x8;
typedef __attribute__((ext_vector_type(8))) short short8;
typedef __attribute__((ext_vector_type(4))) float f32x4;

#define D_DIM 4096
#define M_TOK 8192
#define BM 128
#define BN 128
#define BK 64

// exact round-to-nearest-even fp32 -> bf16 (inputs finite)
__device__ __forceinline__ u16 f2bf(float f) {
  unsigned u = __builtin_bit_cast(unsigned, f);
  u += 0x7fffu + ((u >> 16) & 1u);
  return (u16)(u >> 16);
}

// direct global->LDS DMA, 16B per lane; LDS dest is wave-uniform base + lane*16
#define LOAD_LDS16(gp, lp)                                                     \
  __builtin_amdgcn_global_load_lds(                                            \
      (const __attribute__((address_space(1))) void*)((const void*)(gp)),      \
      (__attribute__((address_space(3))) void*)((void*)(lp)), 16, 0, 0)

// ---------------- abs-mean (two-pass, deterministic) ----------------
__global__ void abs_partial_k(const float* __restrict__ w, float* __restrict__ partial) {
  const int n4 = (D_DIM * D_DIM) / 4;
  float s = 0.f;
  for (int i = blockIdx.x * 256 + threadIdx.x; i < n4; i += 1024 * 256) {
    float4 v = ((const float4*)w)[i];
    s += fabsf(v.x) + fabsf(v.y) + fabsf(v.z) + fabsf(v.w);
  }
#pragma unroll
  for (int o = 32; o > 0; o >>= 1) s += __shfl_down(s, o, 64);
  __shared__ float sm[4];
  if ((threadIdx.x & 63) == 0) sm[threadIdx.x >> 6] = s;
  __syncthreads();
  if (threadIdx.x == 0) partial[blockIdx.x] = sm[0] + sm[1] + sm[2] + sm[3];
}

__global__ void finalize_scale_k(const float* __restrict__ partial, float* __restrict__ scale) {
  float s = 0.f;
  for (int i = threadIdx.x; i < 1024; i += 256) s += partial[i];
#pragma unroll
  for (int o = 32; o > 0; o >>= 1) s += __shfl_down(s, o, 64);
  __shared__ float sm[4];
  if ((threadIdx.x & 63) == 0) sm[threadIdx.x >> 6] = s;
  __syncthreads();
  if (threadIdx.x == 0)
    scale[0] = (sm[0] + sm[1] + sm[2] + sm[3]) * (1.0f / 16777216.0f) + 1e-8f;
}

// ---------------- ternarize: clip(round(w/scale),-1,1) -> bf16 ----------------
__global__ void ternarize_k(const float* __restrict__ w, u16* __restrict__ t,
                            const float* __restrict__ scale) {
  const float sc = scale[0];
  int i = blockIdx.x * 256 + threadIdx.x;  // grid covers n/4 exactly
  float4 v = ((const float4*)w)[i];
  ushort4 o;
  o.x = f2bf(fminf(fmaxf(rintf(v.x / sc), -1.f), 1.f));
  o.y = f2bf(fminf(fmaxf(rintf(v.y / sc), -1.f), 1.f));
  o.z = f2bf(fminf(fmaxf(rintf(v.z / sc), -1.f), 1.f));
  o.w = f2bf(fminf(fmaxf(rintf(v.w / sc), -1.f), 1.f));
  ((ushort4*)t)[i] = o;
}

// ---------------- fused RMSNorm + SiLU, fp32 -> bf16 ----------------
__global__ void rms_silu_k(const float* __restrict__ x, u16* __restrict__ h) {
  const int row = blockIdx.x;
  const float4* xr = (const float4*)(x + (size_t)row * D_DIM);
  float4 v[4];
  float ss = 0.f;
#pragma unroll
  for (int i = 0; i < 4; ++i) {
    v[i] = xr[threadIdx.x + i * 256];
    ss += v[i].x * v[i].x + v[i].y * v[i].y + v[i].z * v[i].z + v[i].w * v[i].w;
  }
#pragma unroll
  for (int o = 32; o > 0; o >>= 1) ss += __shfl_down(ss, o, 64);
  __shared__ float sm[4];
  if ((threadIdx.x & 63) == 0) sm[threadIdx.x >> 6] = ss;
  __syncthreads();
  const float ms = (sm[0] + sm[1] + sm[2] + sm[3]) * (1.0f / (float)D_DIM);
  const float r = rsqrtf(ms + 1.1920929e-7f);  // eps = finfo(f32).eps
  ushort4* hr = (ushort4*)(h + (size_t)row * D_DIM);
#pragma unroll
  for (int i = 0; i < 4; ++i) {
    float z0 = v[i].x * r, z1 = v[i].y * r, z2 = v[i].z * r, z3 = v[i].w * r;
    ushort4 o;
    o.x = f2bf(z0 / (1.f + __expf(-z0)));
    o.y = f2bf(z1 / (1.f + __expf(-z1)));
    o.z = f2bf(z2 / (1.f + __expf(-z2)));
    o.w = f2bf(z3 / (1.f + __expf(-z3)));
    hr[threadIdx.x + i * 256] = o;
  }
}

// ---------------- bf16 GEMM: C[M][N] = A[M][K] * B[N][K]^T ----------------
// 128x128 tile, BK=64, 4 waves, each wave 4x4 grid of 16x16x32 MFMA tiles.
// Staging via global_load_lds width=16, XOR k-block swizzle to kill LDS bank
// conflicts on the ds_read_b128 fragment loads (2-way residual = free, m136).
__global__ __launch_bounds__(256) void gemm_bt_k(
    const u16* __restrict__ A, const u16* __restrict__ B, float* __restrict__ C,
    int M, int N, int K) {
  __shared__ u16 As[BM * BK];  // 16 KB, row-major [128][64], k-blocks swizzled
  __shared__ u16 Bs[BN * BK];  // 16 KB

  const int tid = threadIdx.x;
  const int wave = tid >> 6;
  const int lane = tid & 63;

  const int bm = blockIdx.x * BM;
  const int bn = blockIdx.y * BN;
  const int wm = (wave >> 1) * 64;
  const int wn = (wave & 1) * 64;

  // staging: chunk = 8 rows x 64B; lane l -> row (l>>3), k-block (l&7)^(l>>3)
  const int srow = lane >> 3;
  const int sblk = (lane & 7) ^ srow;

  const size_t ldK = (size_t)K;
  const u16* Abase = A + (size_t)bm * ldK;
  const u16* Bbase = B + (size_t)bn * ldK;

  f32x4 acc[4][4];
#pragma unroll
  for (int i = 0; i < 4; ++i)
#pragma unroll
    for (int j = 0; j < 4; ++j) acc[i][j] = {0.f, 0.f, 0.f, 0.f};

  const int fr = lane & 15;  // fragment row
  const int fq = lane >> 4;  // quad: k-block within 32-k group

  for (int k0 = 0; k0 < K; k0 += BK) {
    __syncthreads();
#pragma unroll
    for (int i = 0; i < 4; ++i) {
      const int c = wave * 4 + i;              // chunk 0..15
      const int row = c * 8 + srow;            // tile row 0..127
      const size_t goff = (size_t)row * ldK + (size_t)(k0 + sblk * 8);
      LOAD_LDS16(Abase + goff, &As[c * 512]);  // 512 u16 = 1 KB chunk
      LOAD_LDS16(Bbase + goff, &Bs[c * 512]);
    }
    __syncthreads();

#pragma unroll
    for (int kk = 0; kk < 2; ++kk) {  // two 32-k MFMA steps per BK=64
      bf16x8 af[4], bfr[4];
#pragma unroll
      for (int mi = 0; mi < 4; ++mi) {
        const int r = wm + mi * 16 + fr;
        const int b = kk * 4 + fq;
        short8 s = *(const short8*)&As[r * BK + ((b ^ (r & 7)) << 3)];
        af[mi] = __builtin_bit_cast(bf16x8, s);
      }
#pragma unroll
      for (int ni = 0; ni < 4; ++ni) {
        const int r = wn + ni * 16 + fr;
        const int b = kk * 4 + fq;
        short8 s = *(const short8*)&Bs[r * BK + ((b ^ (r & 7)) << 3)];
        bfr[ni] = __builtin_bit_cast(bf16x8, s);
      }
#pragma unroll
      for (int mi = 0; mi < 4; ++mi)
#pragma unroll
        for (int ni = 0; ni < 4; ++ni)
          acc[mi][ni] = __builtin_amdgcn_mfma_f32_16x16x32_bf16(
              af[mi], bfr[ni], acc[mi][ni], 0, 0, 0);
    }
  }

  // epilogue: C/D layout col=lane&15, row=(lane>>4)*4+reg (m89-verified)
  const int crow0 = bm + wm + (lane >> 4) * 4;
  const int ccol0 = bn + wn + (lane & 15);
#pragma unroll
  for (int mi = 0; mi < 4; ++mi)
#pragma unroll
    for (int ni = 0; ni < 4; ++ni)
#pragma unroll
      for (int r = 0; r < 4; ++r)
        C[(size_t)(crow0 + mi * 16 + r) * N + (ccol0 + ni * 16)] = acc[mi][ni][r];
}

// ---------------- driver ----------------
extern "C" void kernel_launch(void* const* d_in, const int* in_sizes, int n_in,
                              void* d_out, int out_size, void* d_ws, size_t ws_size,
                              hipStream_t stream) {
  const float* x = (const float*)d_in[0];
  const float* w[3] = {(const float*)d_in[1], (const float*)d_in[2], (const float*)d_in[3]};

  // ws layout (~235 MB): scale | partials | ternary bf16 (reused) | h bf16 | x-mid f32
  char* ws = (char*)d_ws;
  float* scale = (float*)ws;                                   // 16 B
  float* partial = (float*)(ws + 256);                         // 4 KB
  u16* tW = (u16*)(ws + 8192);                                 // 32 MB
  u16* h = (u16*)(ws + 8192 + 33554432);                       // 64 MB
  float* xmid = (float*)(ws + 8192 + 33554432 + 67108864);     // 128 MB

  const float* cur = x;
  for (int l = 0; l < 3; ++l) {
    abs_partial_k<<<1024, 256, 0, stream>>>(w[l], partial);
    finalize_scale_k<<<1, 256, 0, stream>>>(partial, scale);
    ternarize_k<<<(D_DIM * D_DIM) / 4 / 256, 256, 0, stream>>>(w[l], tW, scale);
    rms_silu_k<<<M_TOK, 256, 0, stream>>>(cur, h);
    float* outp = (l == 2) ? (float*)d_out : xmid;
    dim3 grid(M_TOK / BM, D_DIM / BN);
    gemm_bt_k<<<grid, 256, 0, stream>>>(h, tW, outp, M_TOK, D_DIM, D_DIM);
    cur = xmid;
  }
}

// Round 2
// 1300.861 us; speedup vs baseline: 1.2426x; 1.2426x over previous
//
#include <hip/hip_runtime.h>
#include <stdint.h>

typedef unsigned short u16;
typedef __attribute__((ext_vector_type(8))) __bf16 bf16x8;
typedef __attribute__((ext_vector_type(8))) short short8;
typedef __attribute__((ext_vector_type(4))) float f32x4;

#define D_DIM 4096
#define M_TOK 8192
#define BM 128
#define BN 128
#define BK 64

// exact round-to-nearest-even fp32 -> bf16 (inputs finite)
__device__ __forceinline__ u16 f2bf(float f) {
  unsigned u = __builtin_bit_cast(unsigned, f);
  u += 0x7fffu + ((u >> 16) & 1u);
  return (u16)(u >> 16);
}
__device__ __forceinline__ float bf2f(u16 b) {
  unsigned u = ((unsigned)b) << 16;
  return __builtin_bit_cast(float, u);
}

// direct global->LDS DMA, 16B per lane; LDS dest is wave-uniform base + lane*16
#define LOAD_LDS16(gp, lp)                                                     \
  __builtin_amdgcn_global_load_lds(                                            \
      (const __attribute__((address_space(1))) void*)((const void*)(gp)),      \
      (__attribute__((address_space(3))) void*)((void*)(lp)), 16, 0, 0)

// ---------------- abs-mean (two-pass, deterministic) ----------------
__global__ void abs_partial_k(const float* __restrict__ w, float* __restrict__ partial) {
  const int n4 = (D_DIM * D_DIM) / 4;
  float s = 0.f;
  for (int i = blockIdx.x * 256 + threadIdx.x; i < n4; i += 1024 * 256) {
    float4 v = ((const float4*)w)[i];
    s += fabsf(v.x) + fabsf(v.y) + fabsf(v.z) + fabsf(v.w);
  }
#pragma unroll
  for (int o = 32; o > 0; o >>= 1) s += __shfl_down(s, o, 64);
  __shared__ float sm[4];
  if ((threadIdx.x & 63) == 0) sm[threadIdx.x >> 6] = s;
  __syncthreads();
  if (threadIdx.x == 0) partial[blockIdx.x] = sm[0] + sm[1] + sm[2] + sm[3];
}

__global__ void finalize_scale_k(const float* __restrict__ partial, float* __restrict__ scale) {
  float s = 0.f;
  for (int i = threadIdx.x; i < 1024; i += 256) s += partial[i];
#pragma unroll
  for (int o = 32; o > 0; o >>= 1) s += __shfl_down(s, o, 64);
  __shared__ float sm[4];
  if ((threadIdx.x & 63) == 0) sm[threadIdx.x >> 6] = s;
  __syncthreads();
  if (threadIdx.x == 0)
    scale[0] = (sm[0] + sm[1] + sm[2] + sm[3]) * (1.0f / 16777216.0f) + 1e-8f;
}

// ---------------- ternarize: clip(round(w/scale),-1,1) -> bf16 ----------------
__global__ void ternarize_k(const float* __restrict__ w, u16* __restrict__ t,
                            const float* __restrict__ scale) {
  const float sc = scale[0];
  int i = blockIdx.x * 256 + threadIdx.x;  // grid covers n/4 exactly
  float4 v = ((const float4*)w)[i];
  ushort4 o;
  o.x = f2bf(fminf(fmaxf(rintf(v.x / sc), -1.f), 1.f));
  o.y = f2bf(fminf(fmaxf(rintf(v.y / sc), -1.f), 1.f));
  o.z = f2bf(fminf(fmaxf(rintf(v.z / sc), -1.f), 1.f));
  o.w = f2bf(fminf(fmaxf(rintf(v.w / sc), -1.f), 1.f));
  ((ushort4*)t)[i] = o;
}

// ---------------- fused RMSNorm + SiLU -> bf16 ----------------
__global__ void rms_silu_f32_k(const float* __restrict__ x, u16* __restrict__ h) {
  const int row = blockIdx.x;
  const float4* xr = (const float4*)(x + (size_t)row * D_DIM);
  float4 v[4];
  float ss = 0.f;
#pragma unroll
  for (int i = 0; i < 4; ++i) {
    v[i] = xr[threadIdx.x + i * 256];
    ss += v[i].x * v[i].x + v[i].y * v[i].y + v[i].z * v[i].z + v[i].w * v[i].w;
  }
#pragma unroll
  for (int o = 32; o > 0; o >>= 1) ss += __shfl_down(ss, o, 64);
  __shared__ float sm[4];
  if ((threadIdx.x & 63) == 0) sm[threadIdx.x >> 6] = ss;
  __syncthreads();
  const float ms = (sm[0] + sm[1] + sm[2] + sm[3]) * (1.0f / (float)D_DIM);
  const float r = rsqrtf(ms + 1.1920929e-7f);  // eps = finfo(f32).eps
  ushort4* hr = (ushort4*)(h + (size_t)row * D_DIM);
#pragma unroll
  for (int i = 0; i < 4; ++i) {
    float z0 = v[i].x * r, z1 = v[i].y * r, z2 = v[i].z * r, z3 = v[i].w * r;
    ushort4 o;
    o.x = f2bf(z0 / (1.f + __expf(-z0)));
    o.y = f2bf(z1 / (1.f + __expf(-z1)));
    o.z = f2bf(z2 / (1.f + __expf(-z2)));
    o.w = f2bf(z3 / (1.f + __expf(-z3)));
    hr[threadIdx.x + i * 256] = o;
  }
}

__global__ void rms_silu_bf16_k(const u16* __restrict__ x, u16* __restrict__ h) {
  const int row = blockIdx.x;
  const ushort4* xr = (const ushort4*)(x + (size_t)row * D_DIM);
  float4 v[4];
  float ss = 0.f;
#pragma unroll
  for (int i = 0; i < 4; ++i) {
    ushort4 b = xr[threadIdx.x + i * 256];
    v[i] = make_float4(bf2f(b.x), bf2f(b.y), bf2f(b.z), bf2f(b.w));
    ss += v[i].x * v[i].x + v[i].y * v[i].y + v[i].z * v[i].z + v[i].w * v[i].w;
  }
#pragma unroll
  for (int o = 32; o > 0; o >>= 1) ss += __shfl_down(ss, o, 64);
  __shared__ float sm[4];
  if ((threadIdx.x & 63) == 0) sm[threadIdx.x >> 6] = ss;
  __syncthreads();
  const float ms = (sm[0] + sm[1] + sm[2] + sm[3]) * (1.0f / (float)D_DIM);
  const float r = rsqrtf(ms + 1.1920929e-7f);
  ushort4* hr = (ushort4*)(h + (size_t)row * D_DIM);
#pragma unroll
  for (int i = 0; i < 4; ++i) {
    float z0 = v[i].x * r, z1 = v[i].y * r, z2 = v[i].z * r, z3 = v[i].w * r;
    ushort4 o;
    o.x = f2bf(z0 / (1.f + __expf(-z0)));
    o.y = f2bf(z1 / (1.f + __expf(-z1)));
    o.z = f2bf(z2 / (1.f + __expf(-z2)));
    o.w = f2bf(z3 / (1.f + __expf(-z3)));
    hr[threadIdx.x + i * 256] = o;
  }
}

// ---------------- bf16 GEMM: C[M][N] = A[M][K] * B[N][K]^T ----------------
// 128x128 tile, BK=64, 4 waves, each wave 4x4 grid of 16x16x32 MFMA tiles.
// LDS layout: row-major [128][64] u16, with the 8 16B k-slots of each row
// XOR-swizzled by (row&7)  -> zero bank conflicts (measured R1).
// Codegen discipline: exactly 2 precomputed LDS base offsets per matrix
// (kk=0/kk=1); mi/ni strides are compile-time immediates -> ds_read_b128
// with immediate offsets, no per-iteration VALU address math (m97 pattern).
template <typename OUT>
__global__ __launch_bounds__(256) void gemm_bt_k(
    const u16* __restrict__ A, const u16* __restrict__ B, OUT* __restrict__ C,
    int M, int N, int K) {
  __shared__ u16 As[BM * BK];  // 16 KB
  __shared__ u16 Bs[BN * BK];  // 16 KB

  const int tid = threadIdx.x;
  const int wave = tid >> 6;
  const int lane = tid & 63;

  const int bm = blockIdx.x * BM;
  const int bn = blockIdx.y * BN;
  const int wm = (wave >> 1) * 64;
  const int wn = (wave & 1) * 64;

  // ---- precomputed LDS fragment read offsets (u16 units) ----
  const int fr = lane & 15;  // fragment row within 16
  const int fq = lane >> 4;  // k-quad
  const int m3 = fr & 7;
  const int aoff0 = (wm + fr) * BK + ((fq ^ m3) << 3);
  const int aoff1 = (wm + fr) * BK + (((4 + fq) ^ m3) << 3);
  const int boff0 = (wn + fr) * BK + ((fq ^ m3) << 3);
  const int boff1 = (wn + fr) * BK + (((4 + fq) ^ m3) << 3);

  // ---- staging pointers (per-thread, bumped by BK per iter) ----
  const int srow = lane >> 3;
  const int sblk = (lane & 7) ^ srow;
  const size_t ldK = (size_t)K;
  const u16* agp = A + (size_t)(bm + wave * 32 + srow) * ldK + (size_t)(sblk * 8);
  const u16* bgp = B + (size_t)(bn + wave * 32 + srow) * ldK + (size_t)(sblk * 8);
  u16* asd = &As[wave * 2048];  // wave's 4 chunks (4 KB)
  u16* bsd = &Bs[wave * 2048];

  f32x4 acc[4][4];
#pragma unroll
  for (int i = 0; i < 4; ++i)
#pragma unroll
    for (int j = 0; j < 4; ++j) acc[i][j] = {0.f, 0.f, 0.f, 0.f};

  for (int k0 = 0; k0 < K; k0 += BK) {
    __syncthreads();
#pragma unroll
    for (int i = 0; i < 4; ++i) {
      LOAD_LDS16(agp + (size_t)(i * 8) * ldK, asd + i * 512);
      LOAD_LDS16(bgp + (size_t)(i * 8) * ldK, bsd + i * 512);
    }
    agp += BK;
    bgp += BK;
    __syncthreads();

#pragma unroll
    for (int kk = 0; kk < 2; ++kk) {
      const int ao = kk ? aoff1 : aoff0;
      const int bo = kk ? boff1 : boff0;
      bf16x8 af[4], bfr[4];
#pragma unroll
      for (int mi = 0; mi < 4; ++mi)
        af[mi] = __builtin_bit_cast(bf16x8, *(const short8*)&As[ao + mi * (16 * BK)]);
#pragma unroll
      for (int ni = 0; ni < 4; ++ni)
        bfr[ni] = __builtin_bit_cast(bf16x8, *(const short8*)&Bs[bo + ni * (16 * BK)]);
#pragma unroll
      for (int mi = 0; mi < 4; ++mi)
#pragma unroll
        for (int ni = 0; ni < 4; ++ni)
          acc[mi][ni] = __builtin_amdgcn_mfma_f32_16x16x32_bf16(
              af[mi], bfr[ni], acc[mi][ni], 0, 0, 0);
    }
  }

  // epilogue: C/D layout col=lane&15, row=(lane>>4)*4+reg (m89-verified)
  const int crow0 = bm + wm + (lane >> 4) * 4;
  const int ccol0 = bn + wn + (lane & 15);
#pragma unroll
  for (int mi = 0; mi < 4; ++mi)
#pragma unroll
    for (int ni = 0; ni < 4; ++ni)
#pragma unroll
      for (int r = 0; r < 4; ++r) {
        float v = acc[mi][ni][r];
        size_t idx = (size_t)(crow0 + mi * 16 + r) * N + (ccol0 + ni * 16);
        if constexpr (__is_same(OUT, float))
          C[idx] = v;
        else
          C[idx] = f2bf(v);
      }
}

// ---------------- driver ----------------
extern "C" void kernel_launch(void* const* d_in, const int* in_sizes, int n_in,
                              void* d_out, int out_size, void* d_ws, size_t ws_size,
                              hipStream_t stream) {
  const float* x = (const float*)d_in[0];
  const float* w[3] = {(const float*)d_in[1], (const float*)d_in[2], (const float*)d_in[3]};

  // ws layout (~160 MB): scale | partials | ternary bf16 (reused) | h bf16 | xmid bf16
  char* ws = (char*)d_ws;
  float* scale = (float*)ws;                               // 16 B
  float* partial = (float*)(ws + 256);                     // 4 KB
  u16* tW = (u16*)(ws + 8192);                             // 32 MB
  u16* h = (u16*)(ws + 8192 + 33554432);                   // 64 MB
  u16* xmid = (u16*)(ws + 8192 + 33554432 + 67108864);     // 64 MB

  dim3 grid(M_TOK / BM, D_DIM / BN);
  for (int l = 0; l < 3; ++l) {
    abs_partial_k<<<1024, 256, 0, stream>>>(w[l], partial);
    finalize_scale_k<<<1, 256, 0, stream>>>(partial, scale);
    ternarize_k<<<(D_DIM * D_DIM) / 4 / 256, 256, 0, stream>>>(w[l], tW, scale);
    if (l == 0)
      rms_silu_f32_k<<<M_TOK, 256, 0, stream>>>(x, h);
    else
      rms_silu_bf16_k<<<M_TOK, 256, 0, stream>>>(xmid, h);
    if (l == 2)
      gemm_bt_k<float><<<grid, 256, 0, stream>>>(h, tW, (float*)d_out, M_TOK, D_DIM, D_DIM);
    else
      gemm_bt_k<u16><<<grid, 256, 0, stream>>>(h, tW, xmid, M_TOK, D_DIM, D_DIM);
  }
}